// Round 2
// baseline (151.450 us; speedup 1.0000x reference)
//
#include <hip/hip_runtime.h>

#define B_ 4
#define C_ 256
#define H_ 128
#define W_ 128
#define Q_ 100

// ---------------------------------------------------------------------------
// Kernel 1: row cumsum (along x) fused with NCHW -> NHWC transpose.
// Block = (b, y, cb); cb selects 64 channels. 256 threads.
// float4 global loads/stores (16B/lane). LDS tile [64][129] (+1 pad).
// ---------------------------------------------------------------------------
__global__ __launch_bounds__(256) void rowscan_kernel(const float4* __restrict__ x4,
                                                      float4* __restrict__ P4) {
    __shared__ float tile[64][129];
    const int blk = blockIdx.x;            // b*512 + y*4 + cb
    const int cb  = blk & 3;
    const int y   = (blk >> 2) & 127;
    const int b   = blk >> 9;
    const int c0  = cb * 64;
    const int tid = threadIdx.x;

    // Load 64 rows x 32 float4. Per wave: 2 rows x 512B contiguous.
    const float4* src = x4 + ((size_t)((b * C_ + c0) * H_ + y) * W_) / 4;
    #pragma unroll
    for (int i = 0; i < 8; ++i) {
        int idx = i * 256 + tid;
        int cl  = idx >> 5;          // 0..63
        int x4i = idx & 31;          // 0..31
        float4 v = src[(size_t)cl * (H_ * W_ / 4) + x4i];
        tile[cl][4 * x4i + 0] = v.x;
        tile[cl][4 * x4i + 1] = v.y;
        tile[cl][4 * x4i + 2] = v.z;
        tile[cl][4 * x4i + 3] = v.w;
    }
    __syncthreads();

    // Wave-parallel inclusive scan of each 128-wide row (2 elems/lane).
    const int wave = tid >> 6, lane = tid & 63;
    for (int r = wave; r < 64; r += 4) {
        float v0 = tile[r][2 * lane];
        float v1 = tile[r][2 * lane + 1];
        float s  = v0 + v1;
        #pragma unroll
        for (int d = 1; d < 64; d <<= 1) {
            float t = __shfl_up(s, d);
            if (lane >= d) s += t;
        }
        float excl = s - (v0 + v1);
        tile[r][2 * lane]     = excl + v0;
        tile[r][2 * lane + 1] = s;
    }
    __syncthreads();

    // Write NHWC as float4 along c: P[((b*H+y)*W + x)*C + c].
    // Per wave: 4 segments of 256B (16 lanes x 16B contiguous).
    float4* dst = P4 + ((size_t)(b * H_ + y) * W_) * (C_ / 4);
    #pragma unroll
    for (int i = 0; i < 8; ++i) {
        int idx = i * 256 + tid;
        int cg  = idx & 15;          // 16 groups of 4 channels
        int xx  = idx >> 4;          // 0..127
        float4 o;
        o.x = tile[4 * cg + 0][xx];
        o.y = tile[4 * cg + 1][xx];
        o.z = tile[4 * cg + 2][xx];
        o.w = tile[4 * cg + 3][xx];
        dst[(size_t)xx * (C_ / 4) + (c0 >> 2) + cg] = o;
    }
}

// ---------------------------------------------------------------------------
// Kernel 2: in-place column cumsum (along y) on the NHWC buffer.
// Block = (b, x), 4 waves; wave w owns rows [32w, 32w+32), lane owns 4
// channels (float4). All 32 loads issued up front (32KB in flight per wave),
// local cumsum in registers, wave totals exchanged via LDS, offset fused
// into the stores. Serial chain 128 -> 32.
// ---------------------------------------------------------------------------
__global__ __launch_bounds__(256, 2) void colscan_kernel(float* __restrict__ P) {
    __shared__ float4 tot[4][64];
    const int blk  = blockIdx.x;           // b*W + x
    const int x    = blk & 127;
    const int b    = blk >> 7;
    const int wave = threadIdx.x >> 6;
    const int lane = threadIdx.x & 63;

    // float4 index of (b, y=32*wave, x, c=4*lane)
    float4* p = (float4*)P + ((size_t)((b * H_ + wave * 32) * W_) + x) * (C_ / 4) + lane;
    const size_t stride = (size_t)W_ * (C_ / 4);   // one row of y

    float4 v[32];
    #pragma unroll
    for (int j = 0; j < 32; ++j) v[j] = p[(size_t)j * stride];

    #pragma unroll
    for (int j = 1; j < 32; ++j) {
        v[j].x += v[j - 1].x;
        v[j].y += v[j - 1].y;
        v[j].z += v[j - 1].z;
        v[j].w += v[j - 1].w;
    }

    tot[wave][lane] = v[31];
    __syncthreads();

    float4 off = make_float4(0.f, 0.f, 0.f, 0.f);
    #pragma unroll
    for (int w = 0; w < 3; ++w) {
        if (w < wave) {
            float4 t = tot[w][lane];
            off.x += t.x; off.y += t.y; off.z += t.z; off.w += t.w;
        }
    }

    #pragma unroll
    for (int j = 0; j < 32; ++j) {
        float4 o;
        o.x = v[j].x + off.x;
        o.y = v[j].y + off.y;
        o.z = v[j].z + off.z;
        o.w = v[j].w + off.w;
        p[(size_t)j * stride] = o;
    }
}

// ---------------------------------------------------------------------------
// Kernel 3: RoI gather. Block = (b, q, chalf): 128 channels x 49 bins.
// 800 blocks x 256 threads. Lanes = consecutive c -> 256B coalesced SAT
// loads (L3-resident). obuf[cl*49+bin]: bank = (17*cl+bin)%32 -> 2-way, free.
// Linear float4 writeback (block's out region is contiguous).
// ---------------------------------------------------------------------------
__global__ __launch_bounds__(256) void gather_kernel(const float* __restrict__ S,
                                                     const int* __restrict__ rois,
                                                     float* __restrict__ out) {
    __shared__ float obuf[128 * 49];
    __shared__ int   eg[28];   // ys[7], ye[7], xs[7], xe[7]

    const int bq    = blockIdx.x >> 1;
    const int chalf = blockIdx.x & 1;
    const int b     = bq / Q_;
    const int tid   = threadIdx.x;

    const int* r = rois + (size_t)bq * 5;
    if (tid < 28) {
        int x1 = r[1], y1 = r[2], x2 = r[3], y2 = r[4];
        int Lx = x2 - x1, Ly = y2 - y1;
        int g = tid / 7, k = tid % 7;
        int v;
        if (g == 0)      v = y1 + (k * Ly) / 7;              // ys: floor
        else if (g == 1) v = y1 + ((k + 1) * Ly + 6) / 7;    // ye: ceil
        else if (g == 2) v = x1 + (k * Lx) / 7;              // xs: floor
        else             v = x1 + ((k + 1) * Lx + 6) / 7;    // xe: ceil
        eg[tid] = v;
    }
    __syncthreads();

    const float* Sb = S + (size_t)b * (H_ * W_ * C_);
    const int cl    = tid & 127;             // channel-local 0..127
    const int c     = chalf * 128 + cl;
    const int bst   = tid >> 7;              // 0 or 1

    for (int bin = bst; bin < 49; bin += 2) {
        int oy = bin / 7, ox = bin % 7;
        int ys = eg[oy], ye = eg[7 + oy];
        int xs = eg[14 + ox], xe = eg[21 + ox];
        float s11 = Sb[((size_t)(ye - 1) * W_ + (xe - 1)) * C_ + c];
        float s01 = (ys > 0) ? Sb[((size_t)(ys - 1) * W_ + (xe - 1)) * C_ + c] : 0.f;
        float s10 = (xs > 0) ? Sb[((size_t)(ye - 1) * W_ + (xs - 1)) * C_ + c] : 0.f;
        float s00 = (ys > 0 && xs > 0)
                      ? Sb[((size_t)(ys - 1) * W_ + (xs - 1)) * C_ + c] : 0.f;
        float area = (float)((ye - ys) * (xe - xs));
        obuf[cl * 49 + bin] = (s11 - s01 - s10 + s00) / area;
    }
    __syncthreads();

    // Block's output region: out[bq*C*49 + chalf*128*49 .. +128*49) contiguous.
    const float4* ob4 = (const float4*)obuf;
    float4* dst = (float4*)(out + (size_t)bq * (C_ * 49) + (size_t)chalf * (128 * 49));
    for (int i = tid; i < (128 * 49) / 4; i += 256) dst[i] = ob4[i];
}

extern "C" void kernel_launch(void* const* d_in, const int* in_sizes, int n_in,
                              void* d_out, int out_size, void* d_ws, size_t ws_size,
                              hipStream_t stream) {
    const float* x    = (const float*)d_in[0];
    const int*   rois = (const int*)d_in[1];
    float*       outp = (float*)d_out;
    float*       P    = (float*)d_ws;   // 64 MiB NHWC SAT

    rowscan_kernel<<<B_ * H_ * 4, 256, 0, stream>>>((const float4*)x, (float4*)P);
    colscan_kernel<<<B_ * W_, 256, 0, stream>>>(P);
    gather_kernel<<<B_ * Q_ * 2, 256, 0, stream>>>(P, rois, outp);
}